// Round 1
// baseline (1082.882 us; speedup 1.0000x reference)
//
#include <hip/hip_runtime.h>
#include <math.h>

// Problem constants
#define L     880      // state dim
#define LP    896      // padded (64*14 = 16*56) so GEMM tiles need no guards
#define NC    56       // padded col count per time-slab: 48 B-cols, 1 theta0, 4 sig, 3 zero-pad
#define DS    48
#define TT    64
#define NB    4
#define OUTD  96

// ws layout (float offsets)
#define OFF_AT    0                         // 896*896 = 802816
#define OFF_A2T   802816
#define OFF_A4T   1605632
#define OFF_WSEQ  2408448                   // 64 slabs * NC * LP = 3211264
#define OFF_PART  5619712                   // 4 * 256 * LP = 917504
#define OFF_THET  6537216                   // 256 * LP = 229376
// total 6766592 floats = 25.8 MiB

// ---------------- transpose A -> At (padded, zero-filled) ----------------
__global__ void k_transpose(const float* __restrict__ A, float* __restrict__ At) {
  int idx = blockIdx.x * 256 + threadIdx.x;     // LP*LP elements
  int k = idx / LP, l = idx % LP;
  float v = (k < L && l < L) ? A[l * L + k] : 0.f;
  At[k * LP + l] = v;
}

// ---------------- build W0 slab ----------------
// cols 0..47 = B[:,c]; col 48 = theta0; cols 49..52 = -B @ xs[b,0,:]; 53..55 = 0
__global__ void k_prep(const float* __restrict__ B, const float* __restrict__ th0,
                       const float* __restrict__ xs, float* __restrict__ Wseq) {
  int idx = blockIdx.x * 256 + threadIdx.x;     // NC*LP
  int c = idx / LP, l = idx % LP;
  float v = 0.f;
  if (l < L) {
    if (c < DS) v = B[l * DS + c];
    else if (c == DS) v = th0[l];
    else if (c < 53) {
      int b = c - 49;
      float s = 0.f;
      for (int d = 0; d < DS; ++d) s += B[l * DS + d] * xs[(b * TT) * DS + d];
      v = -s;
    }
  }
  Wseq[c * LP + l] = v;
}

// ---------------- square (transposed-operator) GEMM: C = X*X, 896^3 ----------------
// BM=64 (rows i), BN=32 (cols j), BK=16. grid (28, 14). C[i][j] = sum_m X[i][m]*X[m][j].
__global__ __launch_bounds__(256) void k_sq(const float* __restrict__ X, float* __restrict__ C) {
  __shared__ float Xa[64][17];
  __shared__ float Xb[16][36];
  int tid = threadIdx.x;
  int j0 = blockIdx.x * 32, i0 = blockIdx.y * 64;
  int tx = tid & 15, ty = tid >> 4;       // cols tx*2..+1, rows ty*4..+3
  float acc[4][2] = {};
  for (int k0 = 0; k0 < LP; k0 += 16) {
    __syncthreads();
#pragma unroll
    for (int i = 0; i < 4; ++i) {         // stage Xa 64x16
      int el = tid + i * 256, r = el >> 4, kk = el & 15;
      Xa[r][kk] = X[(i0 + r) * LP + k0 + kk];
    }
#pragma unroll
    for (int i = 0; i < 2; ++i) {         // stage Xb 16x32
      int el = tid + i * 256, kk = el >> 5, c = el & 31;
      Xb[kk][c] = X[(k0 + kk) * LP + j0 + c];
    }
    __syncthreads();
#pragma unroll
    for (int kk = 0; kk < 16; ++kk) {
      float b0 = Xb[kk][tx * 2], b1 = Xb[kk][tx * 2 + 1];
#pragma unroll
      for (int r = 0; r < 4; ++r) {
        float a = Xa[ty * 4 + r][kk];
        acc[r][0] += a * b0;
        acc[r][1] += a * b1;
      }
    }
  }
#pragma unroll
  for (int r = 0; r < 4; ++r) {
    C[(i0 + ty * 4 + r) * LP + j0 + tx * 2]     = acc[r][0];
    C[(i0 + ty * 4 + r) * LP + j0 + tx * 2 + 1] = acc[r][1];
  }
}

// ---------------- chain step: Wout_p = G * Win_p, out[c][l] = sum_k Gt[k][l]*Win[c][k] ----------------
// 4 cols/thread (NC=56 divisible by 4, quads never straddle a parity slab).
// grid = nPar * 49 blocks of 256 (threads = nPar * 14 * LP).
__global__ __launch_bounds__(256) void k_chain(const float* __restrict__ Gt,
                                               const float* __restrict__ Win,
                                               float* __restrict__ Wout) {
  int idx = blockIdx.x * 256 + threadIdx.x;
  int l = idx % LP;
  int q = idx / LP;
  int c0 = q * 4;
  int p = c0 / NC;
  int c = c0 - p * NC;
  const float* w = Win + (p * NC + c) * LP;
  float acc[4][2] = {};
  for (int k = 0; k < LP; k += 8) {
    float g0 = Gt[(k + 0) * LP + l];
    float g1 = Gt[(k + 1) * LP + l];
    float g2 = Gt[(k + 2) * LP + l];
    float g3 = Gt[(k + 3) * LP + l];
    float g4 = Gt[(k + 4) * LP + l];
    float g5 = Gt[(k + 5) * LP + l];
    float g6 = Gt[(k + 6) * LP + l];
    float g7 = Gt[(k + 7) * LP + l];
#pragma unroll
    for (int cc = 0; cc < 4; ++cc) {
      float4 wa = *(const float4*)(w + cc * LP + k);
      float4 wb = *(const float4*)(w + cc * LP + k + 4);
      acc[cc][0] += g0 * wa.x; acc[cc][0] += g1 * wa.y;
      acc[cc][0] += g2 * wa.z; acc[cc][0] += g3 * wa.w;
      acc[cc][1] += g4 * wb.x; acc[cc][1] += g5 * wb.y;
      acc[cc][1] += g6 * wb.z; acc[cc][1] += g7 * wb.w;
    }
  }
  float* wo = Wout + (p * NC + c) * LP + l;
#pragma unroll
  for (int cc = 0; cc < 4; ++cc) wo[cc * LP] = acc[cc][0] + acc[cc][1];
}

// ---------------- circular-conv GEMM: part[chunk][r][l] = sum_{k in chunk} U[r][k]*Kd[k][l] ----------------
// r = b*63+tau (252 + pad), k = j*48+d (3024), l state dim. BM=32, BN=64, BK=16, 4 k-chunks of 768.
__global__ __launch_bounds__(256) void k_conv(const float* __restrict__ Wseq,
                                              const float* __restrict__ xs,
                                              float* __restrict__ part) {
  __shared__ float Us[32][17];
  __shared__ __align__(16) float Ks[16][68];
  int tid = threadIdx.x;
  int l0 = blockIdx.x * 64, r0 = blockIdx.y * 32, k00 = blockIdx.z * 768;
  int tx = tid & 15, ty = tid >> 4;       // cols l0+tx*4..+3, rows r0+ty*2..+1
  float acc[2][4] = {};
  for (int ks = 0; ks < 768; ks += 16) {
    int k0 = k00 + ks;
    __syncthreads();
#pragma unroll
    for (int i = 0; i < 2; ++i) {         // stage U 32x16 from xs (circular shift)
      int el = tid + i * 256;
      int r = el >> 4, kk = el & 15;
      int k = k0 + kk;
      float v = 0.f;
      int rr = r0 + r;
      if (rr < 252 && k < 3024) {
        int b = rr / 63, tau = rr - b * 63;
        int j = k / DS, d = k - j * DS;
        int s = tau - j; if (s < 0) s += 63;
        v = xs[(b * TT + s + 1) * DS + d];
      }
      Us[r][kk] = v;
    }
#pragma unroll
    for (int i = 0; i < 4; ++i) {         // stage Kd 16x64 = W_j - W_{j-1} (B-cols), j=0 -> B
      int el = tid + i * 256;
      int kk = el >> 6, ll = el & 63;
      int k = k0 + kk;
      float v = 0.f;
      if (k < 3024) {
        int j = k / DS, d = k - j * DS;
        const float* wp = Wseq + (j * NC + d) * LP + l0 + ll;
        v = wp[0];
        if (j > 0) v -= *(wp - NC * LP);
      }
      Ks[kk][ll] = v;
    }
    __syncthreads();
#pragma unroll
    for (int kk = 0; kk < 16; ++kk) {
      float a0 = Us[ty * 2 + 0][kk];
      float a1 = Us[ty * 2 + 1][kk];
      float4 bv = *(const float4*)&Ks[kk][tx * 4];
      acc[0][0] += a0 * bv.x; acc[0][1] += a0 * bv.y; acc[0][2] += a0 * bv.z; acc[0][3] += a0 * bv.w;
      acc[1][0] += a1 * bv.x; acc[1][1] += a1 * bv.y; acc[1][2] += a1 * bv.z; acc[1][3] += a1 * bv.w;
    }
  }
  float* pp = part + blockIdx.z * (256 * LP);
#pragma unroll
  for (int i = 0; i < 2; ++i)
#pragma unroll
    for (int jj = 0; jj < 4; ++jj)
      pp[(r0 + ty * 2 + i) * LP + l0 + tx * 4 + jj] = acc[i][jj];
}

// ---------------- assemble thetas: 4 partials + phi0, prepend theta0 row ----------------
__global__ void k_assemble(const float* __restrict__ part, const float* __restrict__ Wseq,
                           const float* __restrict__ th0, float* __restrict__ thetas) {
  int idx = blockIdx.x * 256 + threadIdx.x;     // 256 * LP
  int l = idx % LP;
  int bt = idx / LP;          // b*64 + t
  int b = bt >> 6, t = bt & 63;
  float v = 0.f;
  if (l < L) {
    if (t == 0) v = th0[l];
    else {
      int r = b * 63 + (t - 1);
      v = part[0 * 256 * LP + r * LP + l] + part[1 * 256 * LP + r * LP + l]
        + part[2 * 256 * LP + r * LP + l] + part[3 * 256 * LP + r * LP + l];
      int tau = t - 1;
      v += Wseq[(tau * NC + 48) * LP + l];              // A^tau @ theta0
      int tw = (tau + 62) % 63;                          // (tau-1) mod 63
      v += Wseq[(tw * NC + 49 + b) * LP + l];            // A^{(tau-1)%63} @ sig1_b
    }
  }
  thetas[bt * LP + l] = v;
}

// ---------------- decode: per (b,t) row -> 96 outputs ----------------
__global__ __launch_bounds__(128) void k_decode(const float* __restrict__ thetas,
                                                const float* __restrict__ ts,
                                                float* __restrict__ out) {
  int bt = blockIdx.x;
  int o = threadIdx.x;
  if (o >= OUTD) return;
  const float* th = thetas + bt * LP;
  float tv = ts[bt];
  float acc = th[784 + o];
#pragma unroll
  for (int i = 0; i < 8; ++i) {
    float h = fmaxf(th[i] * tv + th[8 + i], 0.f);
    acc += th[16 + o * 8 + i] * h;
  }
  float r;
  if (o < DS) r = tanhf(acc);
  else        r = fmaxf(acc, 0.f) + log1pf(expf(-fabsf(acc)));   // stable softplus
  out[bt * OUTD + o] = r;
}

extern "C" void kernel_launch(void* const* d_in, const int* in_sizes, int n_in,
                              void* d_out, int out_size, void* d_ws, size_t ws_size,
                              hipStream_t stream) {
  const float* xs  = (const float*)d_in[0];   // 4*64*48
  const float* ts  = (const float*)d_in[1];   // 4*64
  const float* th0 = (const float*)d_in[2];   // 880
  const float* A   = (const float*)d_in[3];   // 880*880
  const float* B   = (const float*)d_in[4];   // 880*48
  float* out = (float*)d_out;
  float* ws  = (float*)d_ws;

  float* At     = ws + OFF_AT;
  float* A2t    = ws + OFF_A2T;
  float* A4t    = ws + OFF_A4T;
  float* Wseq   = ws + OFF_WSEQ;
  float* part   = ws + OFF_PART;
  float* thetas = ws + OFF_THET;

  const int SLAB = NC * LP;

  k_transpose<<<(LP * LP) / 256, 256, 0, stream>>>(A, At);
  k_prep<<<(NC * LP) / 256, 256, 0, stream>>>(B, th0, xs, Wseq);
  k_sq<<<dim3(28, 14), 256, 0, stream>>>(At, A2t);                   // A^2 (transposed)
  k_chain<<<49, 256, 0, stream>>>(At, Wseq, Wseq + 1 * SLAB);        // W1 = A W0
  k_chain<<<98, 256, 0, stream>>>(A2t, Wseq, Wseq + 2 * SLAB);       // W2,W3 = A^2 [W0,W1]
  k_sq<<<dim3(28, 14), 256, 0, stream>>>(A2t, A4t);                  // A^4 (transposed)
  for (int s = 0; s < 15; ++s)                                       // W_{4s+4..4s+7} = A^4 W_{4s..4s+3}
    k_chain<<<196, 256, 0, stream>>>(A4t, Wseq + (4 * s) * SLAB, Wseq + (4 * s + 4) * SLAB);
  k_conv<<<dim3(14, 8, 4), 256, 0, stream>>>(Wseq, xs, part);
  k_assemble<<<(256 * LP) / 256, 256, 0, stream>>>(part, Wseq, th0, thetas);
  k_decode<<<256, 128, 0, stream>>>(thetas, ts, out);
}

// Round 2
// 608.391 us; speedup vs baseline: 1.7799x; 1.7799x over previous
//
#include <hip/hip_runtime.h>
#include <math.h>

// Problem constants
#define L     880
#define LP    896          // padded state dim (14*64)
#define NC    64           // cols per time-slab: 48 B-cols, 1 theta0, 4 sig, 11 zero-pad
#define SLAB  (NC * LP)    // 57344 floats
#define DS    48
#define TT    64
#define OUTD  96
#define KK3   3024         // 63*48 conv K-dim

// ws layout (float offsets); total 9,418,752 floats = 37.7 MiB
#define OFF_P0    0
#define OFF_P1    802816
#define OFF_P2    1605632
#define OFF_WSEQ  2408448   // 63 slabs * SLAB = 3612672
#define OFF_KD    6021120   // 3024*896 = 2709504
#define OFF_PART  8730624   // 2 * 256 * 896 = 458752
#define OFF_THET  9189376   // 256 * 896

// ---------------- transpose A -> At (operator layout At[k][l] = A[l][k], zero-padded) ----
__global__ void k_transpose(const float* __restrict__ A, float* __restrict__ At) {
  int idx = blockIdx.x * 256 + threadIdx.x;     // LP*LP
  int k = idx / LP, l = idx % LP;
  At[k * LP + l] = (k < L && l < L) ? A[l * L + k] : 0.f;
}

// ---------------- W0 slab: cols 0..47 = B, 48 = theta0, 49..52 = -B@xs[b,0], rest 0 ----
__global__ void k_prep(const float* __restrict__ B, const float* __restrict__ th0,
                       const float* __restrict__ xs, float* __restrict__ Wseq) {
  int idx = blockIdx.x * 256 + threadIdx.x;     // NC*LP
  int c = idx / LP, l = idx % LP;
  float v = 0.f;
  if (l < L) {
    if (c < DS) v = B[l * DS + c];
    else if (c == DS) v = th0[l];
    else if (c < 53) {
      int b = c - 49;
      float s = 0.f;
      for (int d = 0; d < DS; ++d) s += B[l * DS + d] * xs[(b * TT) * DS + d];
      v = -s;
    }
  }
  Wseq[c * LP + l] = v;
}

// ---------------- tiled GEMM: C[m,n] = sum_k Ain[m,k]*Bt[k,n]; N=K=896 fixed -------------
// BM=64: 4x4 per-thread tile; BM=32: 2x4. 256 threads. grid (896/64, M/BM).
template<int BM, int TM>
__global__ __launch_bounds__(256) void k_gemm(const float* __restrict__ Ain,
                                              const float* __restrict__ Bt,
                                              float* __restrict__ C) {
  __shared__ float As[16][BM + 4];
  __shared__ float Bs[16][68];
  const int tid = threadIdx.x;
  const int n0 = blockIdx.x * 64;
  const int m0 = blockIdx.y * BM;
  const int tx = tid & 15, ty = tid >> 4;
  float acc[TM][4] = {};
  for (int k0 = 0; k0 < LP; k0 += 16) {
    __syncthreads();
    if constexpr (BM == 64) {                       // stage As[kk][m] (transposed)
      int m = tid >> 2, kk0 = (tid & 3) * 4;
      float4 av = *(const float4*)(Ain + (m0 + m) * LP + k0 + kk0);
      As[kk0 + 0][m] = av.x; As[kk0 + 1][m] = av.y;
      As[kk0 + 2][m] = av.z; As[kk0 + 3][m] = av.w;
    } else {
      int m = tid >> 3, kk0 = (tid & 7) * 2;
      float2 av = *(const float2*)(Ain + (m0 + m) * LP + k0 + kk0);
      As[kk0 + 0][m] = av.x; As[kk0 + 1][m] = av.y;
    }
    {                                               // stage Bs[kk][n]
      int kk = tid >> 4, nn = (tid & 15) * 4;
      *(float4*)&Bs[kk][nn] = *(const float4*)(Bt + (k0 + kk) * LP + n0 + nn);
    }
    __syncthreads();
#pragma unroll
    for (int kk = 0; kk < 16; ++kk) {
      float4 b4 = *(const float4*)&Bs[kk][tx * 4];
      if constexpr (TM == 4) {
        float4 a4 = *(const float4*)&As[kk][ty * 4];
        float a[4] = {a4.x, a4.y, a4.z, a4.w};
#pragma unroll
        for (int r = 0; r < 4; ++r) {
          acc[r][0] += a[r] * b4.x; acc[r][1] += a[r] * b4.y;
          acc[r][2] += a[r] * b4.z; acc[r][3] += a[r] * b4.w;
        }
      } else {
        float2 a2 = *(const float2*)&As[kk][ty * 2];
        float a[2] = {a2.x, a2.y};
#pragma unroll
        for (int r = 0; r < 2; ++r) {
          acc[r][0] += a[r] * b4.x; acc[r][1] += a[r] * b4.y;
          acc[r][2] += a[r] * b4.z; acc[r][3] += a[r] * b4.w;
        }
      }
    }
  }
#pragma unroll
  for (int r = 0; r < TM; ++r) {
    float4 o = {acc[r][0], acc[r][1], acc[r][2], acc[r][3]};
    *(float4*)(C + (m0 + ty * TM + r) * LP + n0 + tx * 4) = o;
  }
}

// ---------------- conv kernel diff: KD[(j,d)][l] = W_j.B[d][l] - W_{j-1}.B[d][l] ---------
__global__ void k_kd(const float* __restrict__ Wseq, float* __restrict__ KD) {
  int idx = blockIdx.x * 256 + threadIdx.x;     // KK3*LP
  int k = idx / LP, l = idx - k * LP;
  int j = k / DS, d = k - j * DS;
  float v = Wseq[(j * NC + d) * LP + l];
  if (j > 0) v -= Wseq[((j - 1) * NC + d) * LP + l];
  KD[idx] = v;
}

// ---------------- circular-conv GEMM: part[z][r][l] = sum_{k in chunk} U[r,k]*KD[k,l] ----
// r = b*63+tau (252), k = j*48+d (3024 in 2 chunks of 1536). BM=32, BN=64, BK=16.
__global__ __launch_bounds__(256) void k_conv(const float* __restrict__ KD,
                                              const float* __restrict__ xs,
                                              float* __restrict__ part) {
  __shared__ float Us[16][36];
  __shared__ float Ks[16][68];
  const int tid = threadIdx.x;
  const int l0 = blockIdx.x * 64;
  const int r0 = blockIdx.y * 32;
  const int k00 = blockIdx.z * 1536;
  const int tx = tid & 15, ty = tid >> 4;
  float acc[2][4] = {};
  for (int ks = 0; ks < 1536; ks += 16) {
    const int k0 = k00 + ks;
    __syncthreads();
    {                                             // stage U (gathered, circular shift)
      int r = tid >> 3, kk0 = (tid & 7) * 2;
      int k = k0 + kk0, rr = r0 + r;
      float2 v = {0.f, 0.f};
      if (rr < 252 && k < KK3) {
        int b = rr / 63, tau = rr - b * 63;
        int j = k / DS, d = k - j * DS;          // d even, d+1 same slab
        int s = tau - j; if (s < 0) s += 63;
        v = *(const float2*)(xs + (b * TT + s + 1) * DS + d);
      }
      Us[kk0 + 0][r] = v.x; Us[kk0 + 1][r] = v.y;
    }
    {                                             // stage KD tile
      int kk = tid >> 4, nn = (tid & 15) * 4;
      int k = k0 + kk;
      float4 bv = {0.f, 0.f, 0.f, 0.f};
      if (k < KK3) bv = *(const float4*)(KD + k * LP + l0 + nn);
      *(float4*)&Ks[kk][nn] = bv;
    }
    __syncthreads();
#pragma unroll
    for (int kk = 0; kk < 16; ++kk) {
      float4 b4 = *(const float4*)&Ks[kk][tx * 4];
      float2 a2 = *(const float2*)&Us[kk][ty * 2];
      acc[0][0] += a2.x * b4.x; acc[0][1] += a2.x * b4.y; acc[0][2] += a2.x * b4.z; acc[0][3] += a2.x * b4.w;
      acc[1][0] += a2.y * b4.x; acc[1][1] += a2.y * b4.y; acc[1][2] += a2.y * b4.z; acc[1][3] += a2.y * b4.w;
    }
  }
  float* pp = part + blockIdx.z * (256 * LP);
#pragma unroll
  for (int i = 0; i < 2; ++i) {
    int rr = r0 + ty * 2 + i;
    if (rr < 252) {
      float4 o = {acc[i][0], acc[i][1], acc[i][2], acc[i][3]};
      *(float4*)(pp + rr * LP + l0 + tx * 4) = o;
    }
  }
}

// ---------------- assemble thetas: part sums + phi0, prepend theta0 row ------------------
__global__ void k_assemble(const float* __restrict__ part, const float* __restrict__ Wseq,
                           const float* __restrict__ th0, float* __restrict__ thetas) {
  int idx = blockIdx.x * 256 + threadIdx.x;     // 256 * LP
  int l = idx % LP;
  int bt = idx / LP;          // b*64 + t
  int b = bt >> 6, t = bt & 63;
  float v = 0.f;
  if (l < L) {
    if (t == 0) v = th0[l];
    else {
      int r = b * 63 + (t - 1);
      v = part[r * LP + l] + part[256 * LP + r * LP + l];
      int tau = t - 1;
      v += Wseq[(tau * NC + 48) * LP + l];               // A^tau @ theta0
      int tw = (tau + 62) % 63;                           // (tau-1) mod 63
      v += Wseq[(tw * NC + 49 + b) * LP + l];             // A^{(tau-1)%63} @ sig1_b
    }
  }
  thetas[bt * LP + l] = v;
}

// ---------------- decode: per (b,t) row -> 96 outputs ------------------------------------
__global__ __launch_bounds__(128) void k_decode(const float* __restrict__ thetas,
                                                const float* __restrict__ ts,
                                                float* __restrict__ out) {
  int bt = blockIdx.x;
  int o = threadIdx.x;
  if (o >= OUTD) return;
  const float* th = thetas + bt * LP;
  float tv = ts[bt];
  float acc = th[784 + o];
#pragma unroll
  for (int i = 0; i < 8; ++i) {
    float h = fmaxf(th[i] * tv + th[8 + i], 0.f);
    acc += th[16 + o * 8 + i] * h;
  }
  float r;
  if (o < DS) r = tanhf(acc);
  else        r = fmaxf(acc, 0.f) + log1pf(expf(-fabsf(acc)));
  out[bt * OUTD + o] = r;
}

extern "C" void kernel_launch(void* const* d_in, const int* in_sizes, int n_in,
                              void* d_out, int out_size, void* d_ws, size_t ws_size,
                              hipStream_t stream) {
  const float* xs  = (const float*)d_in[0];
  const float* ts  = (const float*)d_in[1];
  const float* th0 = (const float*)d_in[2];
  const float* A   = (const float*)d_in[3];
  const float* B   = (const float*)d_in[4];
  float* out = (float*)d_out;
  float* ws  = (float*)d_ws;

  float* P0     = ws + OFF_P0;     // At, later A8
  float* P1     = ws + OFF_P1;     // A2, later A16
  float* P2     = ws + OFF_P2;     // A4
  float* Wseq   = ws + OFF_WSEQ;
  float* KD     = ws + OFF_KD;
  float* part   = ws + OFF_PART;
  float* thetas = ws + OFF_THET;

  k_transpose<<<(LP * LP) / 256, 256, 0, stream>>>(A, P0);
  k_prep<<<(NC * LP) / 256, 256, 0, stream>>>(B, th0, xs, Wseq);

  k_gemm<32, 2><<<dim3(14, 2),  256, 0, stream>>>(Wseq, P0, Wseq + 1 * SLAB);   // W1   = A   W0
  k_gemm<64, 4><<<dim3(14, 14), 256, 0, stream>>>(P0, P0, P1);                  // A2
  k_gemm<32, 2><<<dim3(14, 4),  256, 0, stream>>>(Wseq, P1, Wseq + 2 * SLAB);   // W2,3 = A2  W0,1
  k_gemm<64, 4><<<dim3(14, 14), 256, 0, stream>>>(P1, P1, P2);                  // A4
  k_gemm<32, 2><<<dim3(14, 8),  256, 0, stream>>>(Wseq, P2, Wseq + 4 * SLAB);   // W4..7
  k_gemm<64, 4><<<dim3(14, 14), 256, 0, stream>>>(P2, P2, P0);                  // A8 (At dead)
  k_gemm<64, 4><<<dim3(14, 8),  256, 0, stream>>>(Wseq, P0, Wseq + 8 * SLAB);   // W8..15
  k_gemm<64, 4><<<dim3(14, 14), 256, 0, stream>>>(P0, P0, P1);                  // A16 (A2 dead)
  k_gemm<64, 4><<<dim3(14, 16), 256, 0, stream>>>(Wseq, P1, Wseq + 16 * SLAB);  // W16..31
  k_gemm<64, 4><<<dim3(14, 16), 256, 0, stream>>>(Wseq + 16 * SLAB, P1, Wseq + 32 * SLAB); // W32..47
  k_gemm<64, 4><<<dim3(14, 15), 256, 0, stream>>>(Wseq + 32 * SLAB, P1, Wseq + 48 * SLAB); // W48..62

  k_kd<<<(KK3 * LP) / 256, 256, 0, stream>>>(Wseq, KD);
  k_conv<<<dim3(14, 8, 2), 256, 0, stream>>>(KD, xs, part);
  k_assemble<<<(256 * LP) / 256, 256, 0, stream>>>(part, Wseq, th0, thetas);
  k_decode<<<256, 128, 0, stream>>>(thetas, ts, out);
}

// Round 3
// 170.412 us; speedup vs baseline: 6.3545x; 3.5701x over previous
//
#include <hip/hip_runtime.h>
#include <math.h>

typedef unsigned int uint;
typedef unsigned short ushort;
typedef short s16x8 __attribute__((ext_vector_type(8)));
typedef float f32x4 __attribute__((ext_vector_type(4)));
typedef uint u32x4 __attribute__((ext_vector_type(4)));

#define L     880
#define LP    896
#define NC    64
#define WS    (NC * LP)      // 57344 elements per W slab
#define DS    48
#define OUTD  96
#define KCV   3072           // padded conv K (63*48 = 3024 real)

// ws layout (float offsets)
#define OFF_EN1   0
#define OFF_ET1   401408
#define OFF_EN2   802816
#define OFF_ET2   1204224
#define OFF_EN4   1605632
#define OFF_ET4   2007040
#define OFF_EN8   2408448
#define OFF_ET8   2809856
#define OFF_EN16  3211264
#define OFF_ET16  3612672
#define OFF_WF    4014080    // 63 slabs f32: 3612672
#define OFF_WB    7626752    // 63 slabs bf16: 1806336 floats
#define OFF_KDT   9433088    // 896x3072 bf16: 1376256 floats
#define OFF_U     10809344   // 256x3072 bf16: 393216 floats
#define OFF_PART  11202560   // 6 x 256 x 896 f32
#define OFF_TH    12578816   // 256 x 896 f32
// total 12808192 floats = 51.2 MiB

__device__ inline ushort f2b(float f) {
  uint u = __builtin_bit_cast(uint, f);
  u += 0x7fffu + ((u >> 16) & 1u);
  return (ushort)(u >> 16);
}
__device__ inline float b2f(ushort b) {
  uint u = ((uint)b) << 16;
  return __builtin_bit_cast(float, u);
}

// ---------- E1 = A - 0.99 I  (bf16, natural EN[i][j] and transposed ET[j][i]) ----------
__global__ void k_prepE(const float* __restrict__ A, ushort* __restrict__ EN,
                        ushort* __restrict__ ET) {
  __shared__ float T[64][65];
  const int bi = blockIdx.y * 64, bj = blockIdx.x * 64;
  const int t = threadIdx.x;
  const int r = t >> 2;
#pragma unroll
  for (int i = 0; i < 16; ++i) {
    int c = (t & 3) * 16 + i;
    int gi = bi + r, gj = bj + c;
    float v = (gi < L && gj < L) ? A[gi * L + gj] : 0.f;
    if (gi == gj) v -= 0.99f;
    T[r][c] = v;
  }
  __syncthreads();
#pragma unroll
  for (int i = 0; i < 16; ++i) {
    int c = (t & 3) * 16 + i;
    EN[(bi + r) * LP + bj + c] = f2b(T[r][c]);
    ET[(bj + r) * LP + bi + c] = f2b(T[c][r]);
  }
}

// ---------- W0 slab: cols 0..47 = B-cols, 48 = theta0, 49..52 = -B@xs[b,0] ----------
__global__ void k_prepW0(const float* __restrict__ B, const float* __restrict__ th0,
                         const float* __restrict__ xs, float* __restrict__ WF,
                         ushort* __restrict__ WB) {
  int idx = blockIdx.x * 256 + threadIdx.x;   // NC*LP
  int c = idx / LP, l = idx % LP;
  float v = 0.f;
  if (l < L) {
    if (c < DS) v = B[l * DS + c];
    else if (c == DS) v = th0[l];
    else if (c < 53) {
      int b = c - 49;
      float s = 0.f;
      for (int d = 0; d < DS; ++d) s += B[l * DS + d] * xs[(b * 64) * DS + d];
      v = -s;
    }
  }
  WF[idx] = v;
  WB[idx] = f2b(v);
}

// ---------- MFMA GEMM: C[m][n] = sum_k Aop[m][k] * BopT[n][k]  (both bf16) ----------
// 64x64 tile, BK=32, 256 threads = 4 waves, each wave 32x32 via 2x2 16x16x32 frags.
// EPI 0 (SQ):    v = acc + cs*Eself[m*LP+n]; write outB[m*LP+n], outBtr[n*LP+m]
// EPI 1 (CHAIN): v = acc + cs*WinF[m*LP+n];  write outF[m*LP+n], outB[m*LP+n]
// EPI 2 (CONV):  outF[z*256*LP + m*LP+n] = acc  (K-chunked over blockIdx.z)
template<int EPI>
__global__ __launch_bounds__(256) void k_mfma(
    const ushort* __restrict__ Aop, const ushort* __restrict__ BopT, int K, int kIters,
    float cs, const float* __restrict__ WinF, const ushort* __restrict__ Eself,
    float* __restrict__ outF, ushort* __restrict__ outB, ushort* __restrict__ outBtr) {
  __shared__ __align__(16) ushort As[2][64][40];
  __shared__ __align__(16) ushort Bs[2][64][40];
  const int tid = threadIdx.x;
  const int n0 = blockIdx.x * 64;
  const int m0 = blockIdx.y * 64;
  const int kbase = (EPI == 2) ? blockIdx.z * 512 : 0;
  const int r = tid >> 2;           // staging row 0..63
  const int kq = (tid & 3) * 8;     // staging k-chunk
  const ushort* aptr = Aop + (m0 + r) * K + kbase + kq;
  const ushort* bptr = BopT + (n0 + r) * K + kbase + kq;

  const int wv = tid >> 6;
  const int lane = tid & 63;
  const int wm = (wv >> 1) * 32, wn = (wv & 1) * 32;
  const int lr = lane & 15, lg = lane >> 4;

  f32x4 acc[2][2] = {};
  u32x4 ra = *(const u32x4*)aptr;
  u32x4 rb = *(const u32x4*)bptr;
  for (int it = 0; it < kIters; ++it) {
    const int cur = it & 1;
    *(u32x4*)&As[cur][r][kq] = ra;
    *(u32x4*)&Bs[cur][r][kq] = rb;
    __syncthreads();
    if (it + 1 < kIters) {
      ra = *(const u32x4*)(aptr + (it + 1) * 32);
      rb = *(const u32x4*)(bptr + (it + 1) * 32);
    }
    s16x8 a0 = *(const s16x8*)&As[cur][wm + lr][lg * 8];
    s16x8 a1 = *(const s16x8*)&As[cur][wm + 16 + lr][lg * 8];
    s16x8 b0 = *(const s16x8*)&Bs[cur][wn + lr][lg * 8];
    s16x8 b1 = *(const s16x8*)&Bs[cur][wn + 16 + lr][lg * 8];
    acc[0][0] = __builtin_amdgcn_mfma_f32_16x16x32_bf16(a0, b0, acc[0][0], 0, 0, 0);
    acc[0][1] = __builtin_amdgcn_mfma_f32_16x16x32_bf16(a0, b1, acc[0][1], 0, 0, 0);
    acc[1][0] = __builtin_amdgcn_mfma_f32_16x16x32_bf16(a1, b0, acc[1][0], 0, 0, 0);
    acc[1][1] = __builtin_amdgcn_mfma_f32_16x16x32_bf16(a1, b1, acc[1][1], 0, 0, 0);
  }
  float* outFz = outF;
  if (EPI == 2) outFz = outF + blockIdx.z * (256 * LP);
#pragma unroll
  for (int fm = 0; fm < 2; ++fm)
#pragma unroll
    for (int fn = 0; fn < 2; ++fn)
#pragma unroll
      for (int rr = 0; rr < 4; ++rr) {
        int m = m0 + wm + fm * 16 + lg * 4 + rr;
        int n = n0 + wn + fn * 16 + lr;
        float v = acc[fm][fn][rr];
        if (EPI == 0) {
          v += cs * b2f(Eself[m * LP + n]);
          outB[m * LP + n] = f2b(v);
          outBtr[n * LP + m] = f2b(v);
        } else if (EPI == 1) {
          v += cs * WinF[m * LP + n];
          outF[m * LP + n] = v;
          outB[m * LP + n] = f2b(v);
        } else {
          outFz[m * LP + n] = v;
        }
      }
}

// ---------- KDT[l][j*48+d] = W_j[d][l] - W_{j-1}[d][l]  (bf16, transposed for B-op) ----
__global__ void k_kd(const float* __restrict__ WF, ushort* __restrict__ KDT) {
  __shared__ float D[48][65];
  const int j = blockIdx.x;          // 0..62
  const int l0 = blockIdx.y * 64;
  const float* Wj = WF + j * WS;
  for (int e = threadIdx.x; e < 3072; e += 256) {
    int d = e >> 6, ll = e & 63;
    float v = Wj[d * LP + l0 + ll];
    if (j > 0) v -= Wj[-WS + d * LP + l0 + ll];
    D[d][ll] = v;
  }
  __syncthreads();
  for (int e = threadIdx.x; e < 3072; e += 256) {
    int ll = e / 48, d = e - ll * 48;
    KDT[(l0 + ll) * KCV + j * 48 + d] = f2b(D[d][ll]);
  }
}

// ---------- zero-pad KDT cols 3024..3071 ----------
__global__ void k_kdpad(ushort* __restrict__ KDT) {
  int idx = blockIdx.x * 256 + threadIdx.x;    // 896*48
  int l = idx / 48, d = idx % 48;
  KDT[l * KCV + 3024 + d] = 0;
}

// ---------- U[r][k] = xs[b, ((tau-j)%63)+1, d],  r=(b,tau), k=(j,d)  (bf16) ----------
__global__ void k_u(const float* __restrict__ xs, ushort* __restrict__ U) {
  int idx = blockIdx.x * 256 + threadIdx.x;    // 256*3072
  int rr = idx / KCV, k = idx - rr * KCV;
  ushort v = 0;
  if (rr < 252 && k < 3024) {
    int b = rr / 63, tau = rr - b * 63;
    int j = k / DS, d = k - j * DS;
    int s = tau - j; if (s < 0) s += 63;
    v = f2b(xs[(b * 64 + s + 1) * DS + d]);
  }
  U[idx] = v;
}

// ---------- assemble thetas: 6 conv partials + phi0, prepend theta0 ----------
__global__ void k_assemble(const float* __restrict__ part, const float* __restrict__ WF,
                           const float* __restrict__ th0, float* __restrict__ thetas) {
  int idx = blockIdx.x * 256 + threadIdx.x;    // 256*LP
  int l = idx % LP;
  int bt = idx / LP;
  int b = bt >> 6, t = bt & 63;
  float v = 0.f;
  if (l < L) {
    if (t == 0) v = th0[l];
    else {
      int rr = b * 63 + (t - 1);
      v = part[rr * LP + l];
#pragma unroll
      for (int z = 1; z < 6; ++z) v += part[z * 256 * LP + rr * LP + l];
      int tau = t - 1;
      v += WF[tau * WS + DS * LP + l];                 // A^tau @ theta0
      int tw = (tau + 62) % 63;
      v += WF[tw * WS + (49 + b) * LP + l];            // A^{(tau-1)%63} @ sig1_b
    }
  }
  thetas[bt * LP + l] = v;
}

// ---------- decode ----------
__global__ __launch_bounds__(128) void k_decode(const float* __restrict__ thetas,
                                                const float* __restrict__ ts,
                                                float* __restrict__ out) {
  int bt = blockIdx.x;
  int o = threadIdx.x;
  if (o >= OUTD) return;
  const float* th = thetas + bt * LP;
  float tv = ts[bt];
  float acc = th[784 + o];
#pragma unroll
  for (int i = 0; i < 8; ++i) {
    float h = fmaxf(th[i] * tv + th[8 + i], 0.f);
    acc += th[16 + o * 8 + i] * h;
  }
  float r;
  if (o < DS) r = tanhf(acc);
  else        r = fmaxf(acc, 0.f) + log1pf(expf(-fabsf(acc)));
  out[bt * OUTD + o] = r;
}

extern "C" void kernel_launch(void* const* d_in, const int* in_sizes, int n_in,
                              void* d_out, int out_size, void* d_ws, size_t ws_size,
                              hipStream_t stream) {
  const float* xs  = (const float*)d_in[0];
  const float* ts  = (const float*)d_in[1];
  const float* th0 = (const float*)d_in[2];
  const float* A   = (const float*)d_in[3];
  const float* B   = (const float*)d_in[4];
  float* out = (float*)d_out;
  float* ws  = (float*)d_ws;

  ushort* EN1  = (ushort*)(ws + OFF_EN1);
  ushort* ET1  = (ushort*)(ws + OFF_ET1);
  ushort* EN2  = (ushort*)(ws + OFF_EN2);
  ushort* ET2  = (ushort*)(ws + OFF_ET2);
  ushort* EN4  = (ushort*)(ws + OFF_EN4);
  ushort* ET4  = (ushort*)(ws + OFF_ET4);
  ushort* EN8  = (ushort*)(ws + OFF_EN8);
  ushort* ET8  = (ushort*)(ws + OFF_ET8);
  ushort* EN16 = (ushort*)(ws + OFF_EN16);
  ushort* ET16 = (ushort*)(ws + OFF_ET16);
  float*  WF   = ws + OFF_WF;
  ushort* WB   = (ushort*)(ws + OFF_WB);
  ushort* KDT  = (ushort*)(ws + OFF_KDT);
  ushort* U    = (ushort*)(ws + OFF_U);
  float*  part = ws + OFF_PART;
  float*  thetas = ws + OFF_TH;

  const float c1 = 0.99f;
  const float c2 = c1 * c1, c4 = c2 * c2, c8 = c4 * c4, c16 = c8 * c8;
  const int KI = LP / 32;   // 28

  k_prepE<<<dim3(14, 14), 256, 0, stream>>>(A, EN1, ET1);
  k_prepW0<<<(NC * LP) / 256, 256, 0, stream>>>(B, th0, xs, WF, WB);

  // E2 = 2c1*E1 + E1^2 ; then W1 = c1*W0 + W0*E1
  k_mfma<0><<<dim3(14, 14), 256, 0, stream>>>(EN1, ET1, LP, KI, 2.f * c1, nullptr, EN1, nullptr, EN2, ET2);
  k_mfma<1><<<dim3(14, 1),  256, 0, stream>>>(WB, EN1, LP, KI, c1, WF, nullptr, WF + 1 * WS, WB + 1 * WS, nullptr);
  k_mfma<0><<<dim3(14, 14), 256, 0, stream>>>(EN2, ET2, LP, KI, 2.f * c2, nullptr, EN2, nullptr, EN4, ET4);
  k_mfma<1><<<dim3(14, 2),  256, 0, stream>>>(WB, EN2, LP, KI, c2, WF, nullptr, WF + 2 * WS, WB + 2 * WS, nullptr);
  k_mfma<0><<<dim3(14, 14), 256, 0, stream>>>(EN4, ET4, LP, KI, 2.f * c4, nullptr, EN4, nullptr, EN8, ET8);
  k_mfma<1><<<dim3(14, 4),  256, 0, stream>>>(WB, EN4, LP, KI, c4, WF, nullptr, WF + 4 * WS, WB + 4 * WS, nullptr);
  k_mfma<0><<<dim3(14, 14), 256, 0, stream>>>(EN8, ET8, LP, KI, 2.f * c8, nullptr, EN8, nullptr, EN16, ET16);
  k_mfma<1><<<dim3(14, 8),  256, 0, stream>>>(WB, EN8, LP, KI, c8, WF, nullptr, WF + 8 * WS, WB + 8 * WS, nullptr);
  k_mfma<1><<<dim3(14, 16), 256, 0, stream>>>(WB, EN16, LP, KI, c16, WF, nullptr, WF + 16 * WS, WB + 16 * WS, nullptr);
  k_mfma<1><<<dim3(14, 16), 256, 0, stream>>>(WB + 16 * WS, EN16, LP, KI, c16, WF + 16 * WS, nullptr, WF + 32 * WS, WB + 32 * WS, nullptr);
  k_mfma<1><<<dim3(14, 15), 256, 0, stream>>>(WB + 32 * WS, EN16, LP, KI, c16, WF + 32 * WS, nullptr, WF + 48 * WS, WB + 48 * WS, nullptr);

  k_kd<<<dim3(63, 14), 256, 0, stream>>>(WF, KDT);
  k_kdpad<<<(LP * DS) / 256, 256, 0, stream>>>(KDT);
  k_u<<<(256 * KCV) / 256, 256, 0, stream>>>(xs, U);
  k_mfma<2><<<dim3(14, 4, 6), 256, 0, stream>>>(U, KDT, KCV, 16, 0.f, nullptr, nullptr, part, nullptr, nullptr);

  k_assemble<<<(256 * LP) / 256, 256, 0, stream>>>(part, WF, th0, thetas);
  k_decode<<<256, 128, 0, stream>>>(thetas, ts, out);
}

// Round 4
// 110.687 us; speedup vs baseline: 9.7833x; 1.5396x over previous
//
#include <hip/hip_runtime.h>
#include <math.h>

typedef unsigned int uint;
typedef unsigned short ushort;
typedef short s16x8 __attribute__((ext_vector_type(8)));
typedef float f32x4 __attribute__((ext_vector_type(4)));
typedef uint u32x4 __attribute__((ext_vector_type(4)));

#define L     880
#define LP    896
#define NC    64
#define WS    (NC * LP)      // elements per W slab
#define DS    48
#define OUTD  96
#define KCV   3072           // padded conv K (63*48=3024 real)
#define NZ    3              // conv k-chunks

// ws layout (float offsets). E planes are bf16 LP*LP (=401408 floats each).
// order: EN1,ET1,EN2,ET2,EN4,ET4,EN8,ET8,EN16,ET16,EN32
#define OFF_E    0
#define OFF_WF   4415488                  // 63 slabs f32
#define OFF_WB   (OFF_WF + 63 * WS)       // 63 slabs bf16
#define OFF_KDT  (OFF_WB + 63 * WS / 2)   // 896x3072 bf16
#define OFF_U    (OFF_KDT + LP * KCV / 2) // 256x3072 bf16
#define OFF_PART (OFF_U + 256 * KCV / 2)  // NZ x 256 x 896 f32
// total = OFF_PART + NZ*256*LP = 12292096 floats = 49.2 MiB

__device__ inline ushort f2b(float f) {
  uint u = __builtin_bit_cast(uint, f);
  u += 0x7fffu + ((u >> 16) & 1u);
  return (ushort)(u >> 16);
}
__device__ inline float b2f(ushort b) {
  uint u = ((uint)b) << 16;
  return __builtin_bit_cast(float, u);
}

// ---------- E1 = A - 0.99 I -> EN (natural), ET (transposed), bf16, zero-padded ----------
__global__ __launch_bounds__(256) void k_prepE(const float* __restrict__ A,
                                               ushort* __restrict__ EN,
                                               ushort* __restrict__ ET) {
  __shared__ float T[64][65];
  const int bi = blockIdx.y * 64, bj = blockIdx.x * 64;
  const int tid = threadIdx.x;
  const int r = tid >> 2, c0 = (tid & 3) * 16;
  const int gi = bi + r;
#pragma unroll
  for (int q = 0; q < 4; ++q) {
    int c = c0 + q * 4, gj = bj + c;
    float4 v = {0.f, 0.f, 0.f, 0.f};
    if (gi < L && gj < L) {
      v = *(const float4*)(A + gi * L + gj);
      if (gi == gj)     v.x -= 0.99f;
      if (gi == gj + 1) v.y -= 0.99f;
      if (gi == gj + 2) v.z -= 0.99f;
      if (gi == gj + 3) v.w -= 0.99f;
    }
    T[r][c] = v.x; T[r][c + 1] = v.y; T[r][c + 2] = v.z; T[r][c + 3] = v.w;
  }
  __syncthreads();
  {
    union { ushort s[16]; u32x4 v[2]; } pk;
#pragma unroll
    for (int i = 0; i < 16; ++i) pk.s[i] = f2b(T[r][c0 + i]);
    *(u32x4*)(EN + (size_t)(bi + r) * LP + bj + c0)     = pk.v[0];
    *(u32x4*)(EN + (size_t)(bi + r) * LP + bj + c0 + 8) = pk.v[1];
  }
  {
    union { ushort s[16]; u32x4 v[2]; } pk;
#pragma unroll
    for (int i = 0; i < 16; ++i) pk.s[i] = f2b(T[c0 + i][r]);
    *(u32x4*)(ET + (size_t)(bj + r) * LP + bi + c0)     = pk.v[0];
    *(u32x4*)(ET + (size_t)(bj + r) * LP + bi + c0 + 8) = pk.v[1];
  }
}

// ---------- W0 slab: cols 0..47 = B, 48 = theta0, 49..52 = -B@xs[b,0], rest 0 ----------
__global__ void k_prepW0(const float* __restrict__ B, const float* __restrict__ th0,
                         const float* __restrict__ xs, float* __restrict__ WF,
                         ushort* __restrict__ WB) {
  int idx = blockIdx.x * 256 + threadIdx.x;   // NC*LP
  int c = idx / LP, l = idx % LP;
  float v = 0.f;
  if (l < L) {
    if (c < DS) v = B[l * DS + c];
    else if (c == DS) v = th0[l];
    else if (c < 53) {
      int b = c - 49;
      float s = 0.f;
      for (int d = 0; d < DS; ++d) s += B[l * DS + d] * xs[(b * 64) * DS + d];
      v = -s;
    }
  }
  WF[idx] = v;
  WB[idx] = f2b(v);
}

// ---------- fused ladder launch: [square E_t -> E_2t] (blocks y<ySq)  ||  [chain] ----------
// core GEMM: C[m][n] = sum_k Aop[m][k] * BopT[n][k], 64x64 tile, BK=64, K=LP.
__global__ __launch_bounds__(256) void k_ladder(
    const ushort* __restrict__ sqA, const ushort* __restrict__ sqBT, float cs2,
    ushort* __restrict__ sqOutN, ushort* __restrict__ sqOutT, int ySq,
    const ushort* __restrict__ chA, const ushort* __restrict__ chBT, float csc,
    const float* __restrict__ chWFin, float* __restrict__ chWFout,
    ushort* __restrict__ chWBout) {
  __shared__ __align__(16) ushort As[2][64][72];
  __shared__ __align__(16) ushort Bs[2][64][72];
  const int tid = threadIdx.x;
  const bool isSq = (int)blockIdx.y < ySq;
  const int n0 = blockIdx.x * 64;
  const int m0 = isSq ? blockIdx.y * 64 : ((int)blockIdx.y - ySq) * 64;
  const ushort* Ab = isSq ? sqA : chA;
  const ushort* Bb = isSq ? sqBT : chBT;
  const int r = tid >> 2, kq = (tid & 3) * 16;
  const ushort* aptr = Ab + (size_t)(m0 + r) * LP + kq;
  const ushort* bptr = Bb + (size_t)(n0 + r) * LP + kq;
  const int wv = tid >> 6, lane = tid & 63;
  const int wm = (wv >> 1) * 32, wn = (wv & 1) * 32;
  const int lr = lane & 15, lg = lane >> 4;
  f32x4 acc[2][2] = {};
  u32x4 ra0 = *(const u32x4*)aptr;
  u32x4 ra1 = *(const u32x4*)(aptr + 8);
  u32x4 rb0 = *(const u32x4*)bptr;
  u32x4 rb1 = *(const u32x4*)(bptr + 8);
  const int kI = LP / 64;   // 14
  for (int it = 0; it < kI; ++it) {
    const int cur = it & 1;
    *(u32x4*)&As[cur][r][kq]     = ra0;
    *(u32x4*)&As[cur][r][kq + 8] = ra1;
    *(u32x4*)&Bs[cur][r][kq]     = rb0;
    *(u32x4*)&Bs[cur][r][kq + 8] = rb1;
    __syncthreads();
    if (it + 1 < kI) {
      ra0 = *(const u32x4*)(aptr + (it + 1) * 64);
      ra1 = *(const u32x4*)(aptr + (it + 1) * 64 + 8);
      rb0 = *(const u32x4*)(bptr + (it + 1) * 64);
      rb1 = *(const u32x4*)(bptr + (it + 1) * 64 + 8);
    }
#pragma unroll
    for (int ks = 0; ks < 2; ++ks) {
      s16x8 a0 = *(const s16x8*)&As[cur][wm + lr][ks * 32 + lg * 8];
      s16x8 a1 = *(const s16x8*)&As[cur][wm + 16 + lr][ks * 32 + lg * 8];
      s16x8 b0 = *(const s16x8*)&Bs[cur][wn + lr][ks * 32 + lg * 8];
      s16x8 b1 = *(const s16x8*)&Bs[cur][wn + 16 + lr][ks * 32 + lg * 8];
      acc[0][0] = __builtin_amdgcn_mfma_f32_16x16x32_bf16(a0, b0, acc[0][0], 0, 0, 0);
      acc[0][1] = __builtin_amdgcn_mfma_f32_16x16x32_bf16(a0, b1, acc[0][1], 0, 0, 0);
      acc[1][0] = __builtin_amdgcn_mfma_f32_16x16x32_bf16(a1, b0, acc[1][0], 0, 0, 0);
      acc[1][1] = __builtin_amdgcn_mfma_f32_16x16x32_bf16(a1, b1, acc[1][1], 0, 0, 0);
    }
  }
  if (isSq) {
    // E_2t = E_t^2 + 2c_t*E_t ; write natural + (optionally) transposed via LDS
    ushort (*T)[72] = As[0];
    __syncthreads();
#pragma unroll
    for (int fm = 0; fm < 2; ++fm)
#pragma unroll
      for (int fn = 0; fn < 2; ++fn)
#pragma unroll
        for (int rr = 0; rr < 4; ++rr) {
          int mi = wm + fm * 16 + lg * 4 + rr;
          int ni = wn + fn * 16 + lr;
          float v = acc[fm][fn][rr] + cs2 * b2f(sqA[(size_t)(m0 + mi) * LP + n0 + ni]);
          ushort bv = f2b(v);
          sqOutN[(size_t)(m0 + mi) * LP + n0 + ni] = bv;
          T[ni][mi] = bv;
        }
    if (sqOutT) {
      __syncthreads();
      int rt = tid >> 2, ct0 = (tid & 3) * 16;
      u32x4 o0 = *(const u32x4*)&T[rt][ct0];
      u32x4 o1 = *(const u32x4*)&T[rt][ct0 + 8];
      *(u32x4*)(sqOutT + (size_t)(n0 + rt) * LP + m0 + ct0)     = o0;
      *(u32x4*)(sqOutT + (size_t)(n0 + rt) * LP + m0 + ct0 + 8) = o1;
    }
  } else {
    // W_{t+s} = c_s * W_t + W_t . E_s
#pragma unroll
    for (int fm = 0; fm < 2; ++fm)
#pragma unroll
      for (int fn = 0; fn < 2; ++fn)
#pragma unroll
        for (int rr = 0; rr < 4; ++rr) {
          int m = m0 + wm + fm * 16 + lg * 4 + rr;
          int n = n0 + wn + fn * 16 + lr;
          float v = acc[fm][fn][rr] + csc * chWFin[(size_t)m * LP + n];
          chWFout[(size_t)m * LP + n] = v;
          chWBout[(size_t)m * LP + n] = f2b(v);
        }
  }
}

// ---------- KDT[l][j*48+d] = W_j[d][l] - W_{j-1}[d][l]; j=63 block writes zero pad ----------
__global__ void k_kd(const float* __restrict__ WF, ushort* __restrict__ KDT) {
  __shared__ float D[48][65];
  const int j = blockIdx.x;          // 0..63
  const int l0 = blockIdx.y * 64;
  if (j < 63) {
    const float* Wj = WF + (size_t)j * WS;
    for (int e = threadIdx.x; e < 48 * 64; e += 256) {
      int d = e >> 6, ll = e & 63;
      float v = Wj[d * LP + l0 + ll];
      if (j > 0) v -= Wj[-(int)WS + d * LP + l0 + ll];
      D[d][ll] = v;
    }
  } else {
    for (int e = threadIdx.x; e < 48 * 64; e += 256) { int d = e >> 6, ll = e & 63; D[d][ll] = 0.f; }
  }
  __syncthreads();
  for (int e = threadIdx.x; e < 48 * 64; e += 256) {
    int ll = e / 48, d = e - ll * 48;
    KDT[(size_t)(l0 + ll) * KCV + j * 48 + d] = f2b(D[d][ll]);
  }
}

// ---------- U[r][k] = xs[b, ((tau-j)%63)+1, d], bf16, 4 elems/thread ----------
__global__ void k_u(const float* __restrict__ xs, ushort* __restrict__ U) {
  int idx = (blockIdx.x * 256 + threadIdx.x) * 4;   // 256*KCV total
  int rr = idx / KCV, k = idx - rr * KCV;
  ushort4 v = {0, 0, 0, 0};
  if (rr < 252 && k < 3024) {
    int b = rr / 63, tau = rr - b * 63;
    int j = k / DS, d = k - j * DS;
    int s = tau - j; if (s < 0) s += 63;
    float4 x4 = *(const float4*)(xs + (size_t)(b * 64 + s + 1) * DS + d);
    v.x = f2b(x4.x); v.y = f2b(x4.y); v.z = f2b(x4.z); v.w = f2b(x4.w);
  }
  *(ushort4*)(U + idx) = v;
}

// ---------- conv GEMM: part[z][r][l] = sum_{k in chunk z} U[r][k] * KDT[l][k] ----------
__global__ __launch_bounds__(256) void k_conv(const ushort* __restrict__ U,
                                              const ushort* __restrict__ KDT,
                                              float* __restrict__ part) {
  __shared__ __align__(16) ushort As[2][64][72];
  __shared__ __align__(16) ushort Bs[2][64][72];
  const int tid = threadIdx.x;
  const int n0 = blockIdx.x * 64, m0 = blockIdx.y * 64;
  const int kbase = blockIdx.z * (KCV / NZ);
  const int r = tid >> 2, kq = (tid & 3) * 16;
  const ushort* aptr = U + (size_t)(m0 + r) * KCV + kbase + kq;
  const ushort* bptr = KDT + (size_t)(n0 + r) * KCV + kbase + kq;
  const int wv = tid >> 6, lane = tid & 63;
  const int wm = (wv >> 1) * 32, wn = (wv & 1) * 32;
  const int lr = lane & 15, lg = lane >> 4;
  f32x4 acc[2][2] = {};
  u32x4 ra0 = *(const u32x4*)aptr;
  u32x4 ra1 = *(const u32x4*)(aptr + 8);
  u32x4 rb0 = *(const u32x4*)bptr;
  u32x4 rb1 = *(const u32x4*)(bptr + 8);
  const int kI = (KCV / NZ) / 64;  // 16
  for (int it = 0; it < kI; ++it) {
    const int cur = it & 1;
    *(u32x4*)&As[cur][r][kq]     = ra0;
    *(u32x4*)&As[cur][r][kq + 8] = ra1;
    *(u32x4*)&Bs[cur][r][kq]     = rb0;
    *(u32x4*)&Bs[cur][r][kq + 8] = rb1;
    __syncthreads();
    if (it + 1 < kI) {
      ra0 = *(const u32x4*)(aptr + (it + 1) * 64);
      ra1 = *(const u32x4*)(aptr + (it + 1) * 64 + 8);
      rb0 = *(const u32x4*)(bptr + (it + 1) * 64);
      rb1 = *(const u32x4*)(bptr + (it + 1) * 64 + 8);
    }
#pragma unroll
    for (int ks = 0; ks < 2; ++ks) {
      s16x8 a0 = *(const s16x8*)&As[cur][wm + lr][ks * 32 + lg * 8];
      s16x8 a1 = *(const s16x8*)&As[cur][wm + 16 + lr][ks * 32 + lg * 8];
      s16x8 b0 = *(const s16x8*)&Bs[cur][wn + lr][ks * 32 + lg * 8];
      s16x8 b1 = *(const s16x8*)&Bs[cur][wn + 16 + lr][ks * 32 + lg * 8];
      acc[0][0] = __builtin_amdgcn_mfma_f32_16x16x32_bf16(a0, b0, acc[0][0], 0, 0, 0);
      acc[0][1] = __builtin_amdgcn_mfma_f32_16x16x32_bf16(a0, b1, acc[0][1], 0, 0, 0);
      acc[1][0] = __builtin_amdgcn_mfma_f32_16x16x32_bf16(a1, b0, acc[1][0], 0, 0, 0);
      acc[1][1] = __builtin_amdgcn_mfma_f32_16x16x32_bf16(a1, b1, acc[1][1], 0, 0, 0);
    }
  }
  float* pp = part + (size_t)blockIdx.z * (256 * LP);
#pragma unroll
  for (int fm = 0; fm < 2; ++fm)
#pragma unroll
    for (int fn = 0; fn < 2; ++fn)
#pragma unroll
      for (int rr = 0; rr < 4; ++rr) {
        int m = m0 + wm + fm * 16 + lg * 4 + rr;
        int n = n0 + wn + fn * 16 + lr;
        pp[(size_t)m * LP + n] = acc[fm][fn][rr];
      }
}

// ---------- final: assemble theta row in LDS, then decode 96 outputs ----------
__global__ __launch_bounds__(256) void k_final(const float* __restrict__ part,
                                               const float* __restrict__ WF,
                                               const float* __restrict__ th0,
                                               const float* __restrict__ ts,
                                               float* __restrict__ out) {
  __shared__ float th[LP];
  const int bt = blockIdx.x, b = bt >> 6, t = bt & 63;
  for (int l = threadIdx.x; l < LP; l += 256) {
    float v = 0.f;
    if (l < L) {
      if (t == 0) v = th0[l];
      else {
        int rr = b * 63 + (t - 1);
        v = part[(size_t)rr * LP + l]
          + part[(size_t)(256 * LP) + rr * LP + l]
          + part[(size_t)(2 * 256 * LP) + rr * LP + l];
        int tau = t - 1;
        v += WF[(size_t)tau * WS + DS * LP + l];          // A^tau @ theta0
        int tw = (tau + 62) % 63;
        v += WF[(size_t)tw * WS + (49 + b) * LP + l];     // A^{(tau-1)%63} @ sig1_b
      }
    }
    th[l] = v;
  }
  __syncthreads();
  int o = threadIdx.x;
  if (o < OUTD) {
    float tv = ts[bt];
    float acc = th[784 + o];
#pragma unroll
    for (int i = 0; i < 8; ++i) {
      float h = fmaxf(th[i] * tv + th[8 + i], 0.f);
      acc += th[16 + o * 8 + i] * h;
    }
    float rs;
    if (o < DS) rs = tanhf(acc);
    else        rs = fmaxf(acc, 0.f) + log1pf(expf(-fabsf(acc)));
    out[bt * OUTD + o] = rs;
  }
}

extern "C" void kernel_launch(void* const* d_in, const int* in_sizes, int n_in,
                              void* d_out, int out_size, void* d_ws, size_t ws_size,
                              hipStream_t stream) {
  const float* xs  = (const float*)d_in[0];
  const float* ts  = (const float*)d_in[1];
  const float* th0 = (const float*)d_in[2];
  const float* A   = (const float*)d_in[3];
  const float* B   = (const float*)d_in[4];
  float* out = (float*)d_out;
  float* ws  = (float*)d_ws;

  ushort* EP   = (ushort*)(ws + OFF_E);
  const size_t PL = (size_t)LP * LP;     // plane size in shorts
  ushort* EN1  = EP + 0 * PL;
  ushort* ET1  = EP + 1 * PL;
  ushort* EN2  = EP + 2 * PL;
  ushort* ET2  = EP + 3 * PL;
  ushort* EN4  = EP + 4 * PL;
  ushort* ET4  = EP + 5 * PL;
  ushort* EN8  = EP + 6 * PL;
  ushort* ET8  = EP + 7 * PL;
  ushort* EN16 = EP + 8 * PL;
  ushort* ET16 = EP + 9 * PL;
  ushort* EN32 = EP + 10 * PL;
  float*  WF   = ws + OFF_WF;
  ushort* WB   = (ushort*)(ws + OFF_WB);
  ushort* KDT  = (ushort*)(ws + OFF_KDT);
  ushort* U    = (ushort*)(ws + OFF_U);
  float*  part = ws + OFF_PART;

  const float c1 = 0.99f;
  const float c2 = c1 * c1, c4 = c2 * c2, c8 = c4 * c4, c16 = c8 * c8, c32 = c16 * c16;

  k_prepE<<<dim3(14, 14), 256, 0, stream>>>(A, EN1, ET1);
  k_prepW0<<<(NC * LP) / 256, 256, 0, stream>>>(B, th0, xs, WF, WB);
  k_u<<<(256 * KCV / 4) / 256, 256, 0, stream>>>(xs, U);

  // L1: sq E1->E2 || chain W1 = c1*W0 + W0.E1
  k_ladder<<<dim3(14, 15), 256, 0, stream>>>(EN1, ET1, 2.f * c1, EN2, ET2, 14,
                                             WB, EN1, c1, WF, WF + 1 * WS, WB + (size_t)1 * WS);
  // L2: sq E2->E4 || chain W2,3
  k_ladder<<<dim3(14, 16), 256, 0, stream>>>(EN2, ET2, 2.f * c2, EN4, ET4, 14,
                                             WB, EN2, c2, WF, WF + 2 * WS, WB + (size_t)2 * WS);
  // L3: sq E4->E8 || chain W4..7
  k_ladder<<<dim3(14, 18), 256, 0, stream>>>(EN4, ET4, 2.f * c4, EN8, ET8, 14,
                                             WB, EN4, c4, WF, WF + 4 * WS, WB + (size_t)4 * WS);
  // L4: sq E8->E16 || chain W8..15
  k_ladder<<<dim3(14, 22), 256, 0, stream>>>(EN8, ET8, 2.f * c8, EN16, ET16, 14,
                                             WB, EN8, c8, WF, WF + 8 * WS, WB + (size_t)8 * WS);
  // L5: sq E16->E32 (no transpose needed) || chain W16..31
  k_ladder<<<dim3(14, 30), 256, 0, stream>>>(EN16, ET16, 2.f * c16, EN32, nullptr, 14,
                                             WB, EN16, c16, WF, WF + 16 * WS, WB + (size_t)16 * WS);
  // L6: chain-only W32..62 = c32*W_t + W_t.E32, t=0..30
  k_ladder<<<dim3(14, 31), 256, 0, stream>>>(nullptr, nullptr, 0.f, nullptr, nullptr, 0,
                                             WB, EN32, c32, WF, WF + 32 * WS, WB + (size_t)32 * WS);

  k_kd<<<dim3(64, 14), 256, 0, stream>>>(WF, KDT);
  k_conv<<<dim3(14, 4, NZ), 256, 0, stream>>>(U, KDT, part);
  k_final<<<256, 256, 0, stream>>>(part, WF, th0, ts, out);
}